// Round 2
// baseline (499.579 us; speedup 1.0000x reference)
//
#include <hip/hip_runtime.h>

// SparseCodebook: out[b] = min_k mean_d |codes[b,d] - centroids[cls[b],k,d]|
// B=262144, NUM_CLASSES=1000, K=4, D=256.
//
// R1 analysis: naive order re-reads 4KiB of centroids per sample = 1 GiB of
// gather traffic that thrashes L2 (3.9 MiB table vs 4 MiB/XCD L2, evicted by
// the 256 MiB codes stream) and L3 (codes = 256 MiB = L3 size). Fix: counting
// sort samples by class (3 cheap prep kernels), then process in class order so
// each class's 4 KiB centroid block stays hot in L1/L2. Centroid HBM traffic
// ~1 GiB -> ~4 MB; floor = 269 MB / 6.3 TB/s ~= 43 us.

#define B_TOTAL     262144
#define NUM_CLASSES 1000
#define KC          4
#define DIM         256

// d_ws layout (int32): [0,1024) counts, [1024,2048) cursors, [2048,2048+B) sorted idx
#define WS_NEEDED   ((size_t)(2048 + B_TOTAL) * sizeof(int))

__global__ __launch_bounds__(256) void hist_kernel(
    const int* __restrict__ pred, int* __restrict__ counts)
{
    const int i = blockIdx.x * 256 + threadIdx.x;
    if (i < B_TOTAL) atomicAdd(&counts[pred[i]], 1);
}

__global__ __launch_bounds__(1024) void scan_kernel(
    const int* __restrict__ counts, int* __restrict__ cursors)
{
    __shared__ int sc[1024];
    const int i = threadIdx.x;
    const int v = (i < NUM_CLASSES) ? counts[i] : 0;
    sc[i] = v;
    __syncthreads();
#pragma unroll
    for (int off = 1; off < 1024; off <<= 1) {
        const int t = (i >= off) ? sc[i - off] : 0;
        __syncthreads();
        sc[i] += t;
        __syncthreads();
    }
    if (i < NUM_CLASSES) cursors[i] = sc[i] - v;   // exclusive prefix
}

__global__ __launch_bounds__(256) void scatter_kernel(
    const int* __restrict__ pred, int* __restrict__ cursors,
    int* __restrict__ sorted)
{
    const int i = blockIdx.x * 256 + threadIdx.x;
    if (i < B_TOTAL) {
        const int c   = pred[i];
        const int pos = atomicAdd(&cursors[c], 1);
        sorted[pos] = i;
    }
}

// One wave per sorted position. Consecutive waves share a class -> centroid
// rows (4 KiB/class) hit L1/L2 instead of HBM.
__global__ __launch_bounds__(256) void sparse_codebook_sorted(
    const float* __restrict__ codes,
    const int*   __restrict__ pred_class,
    const float* __restrict__ centroids,
    const int*   __restrict__ sorted,
    float*       __restrict__ out)
{
    const int p    = (blockIdx.x * 256 + threadIdx.x) >> 6;  // sorted position
    const int lane = threadIdx.x & 63;
    if (p >= B_TOTAL) return;

    const int sample = __builtin_amdgcn_readfirstlane(sorted[p]);
    const int cls    = __builtin_amdgcn_readfirstlane(pred_class[sample]);

    const float4* codes4 = (const float4*)codes + (size_t)sample * 64;
    const float4  c      = codes4[lane];

    const float4* cent4 = (const float4*)centroids + (size_t)cls * (KC * DIM / 4);

    float s[KC];
#pragma unroll
    for (int k = 0; k < KC; ++k) {
        const float4 g = cent4[k * 64 + lane];
        s[k] = fabsf(c.x - g.x) + fabsf(c.y - g.y)
             + fabsf(c.z - g.z) + fabsf(c.w - g.w);
    }

#pragma unroll
    for (int off = 32; off > 0; off >>= 1) {
#pragma unroll
        for (int k = 0; k < KC; ++k)
            s[k] += __shfl_xor(s[k], off, 64);
    }

    if (lane == 0) {
        const float m = fminf(fminf(s[0], s[1]), fminf(s[2], s[3]));
        out[sample] = m * (1.0f / (float)DIM);
    }
}

// Fallback (R1 kernel) if workspace is too small for the sort.
__global__ __launch_bounds__(256) void sparse_codebook_direct(
    const float* __restrict__ codes,
    const int*   __restrict__ pred_class,
    const float* __restrict__ centroids,
    float*       __restrict__ out)
{
    const int sample = (blockIdx.x * 256 + threadIdx.x) >> 6;
    const int lane   = threadIdx.x & 63;
    if (sample >= B_TOTAL) return;

    const int cls = __builtin_amdgcn_readfirstlane(pred_class[sample]);
    const float4 c = ((const float4*)codes + (size_t)sample * 64)[lane];
    const float4* cent4 = (const float4*)centroids + (size_t)cls * (KC * DIM / 4);

    float s[KC];
#pragma unroll
    for (int k = 0; k < KC; ++k) {
        const float4 g = cent4[k * 64 + lane];
        s[k] = fabsf(c.x - g.x) + fabsf(c.y - g.y)
             + fabsf(c.z - g.z) + fabsf(c.w - g.w);
    }
#pragma unroll
    for (int off = 32; off > 0; off >>= 1)
#pragma unroll
        for (int k = 0; k < KC; ++k)
            s[k] += __shfl_xor(s[k], off, 64);

    if (lane == 0)
        out[sample] = fminf(fminf(s[0], s[1]), fminf(s[2], s[3])) * (1.0f / (float)DIM);
}

extern "C" void kernel_launch(void* const* d_in, const int* in_sizes, int n_in,
                              void* d_out, int out_size, void* d_ws, size_t ws_size,
                              hipStream_t stream) {
    const float* codes = (const float*)d_in[0];
    const int*   pred  = (const int*)d_in[1];
    const float* cents = (const float*)d_in[2];
    float*       out   = (float*)d_out;

    if (ws_size >= WS_NEEDED) {
        int* counts  = (int*)d_ws;
        int* cursors = counts + 1024;
        int* sorted  = counts + 2048;

        hipMemsetAsync(counts, 0, 1024 * sizeof(int), stream);
        hist_kernel   <<<(B_TOTAL + 255) / 256, 256, 0, stream>>>(pred, counts);
        scan_kernel   <<<1, 1024, 0, stream>>>(counts, cursors);
        scatter_kernel<<<(B_TOTAL + 255) / 256, 256, 0, stream>>>(pred, cursors, sorted);

        const int grid = (B_TOTAL * 64) / 256;  // one wave per sample
        sparse_codebook_sorted<<<grid, 256, 0, stream>>>(codes, pred, cents, sorted, out);
    } else {
        const int grid = (B_TOTAL * 64) / 256;
        sparse_codebook_direct<<<grid, 256, 0, stream>>>(codes, pred, cents, out);
    }
}

// Round 3
// 376.592 us; speedup vs baseline: 1.3266x; 1.3266x over previous
//
#include <hip/hip_runtime.h>

// SparseCodebook: out[b] = min_k mean_d |codes[b,d] - centroids[cls[b],k,d]|
// B=262144, NUM_CLASSES=1000, K=4, D=256.
//
// R2 post-mortem: class-sorting regressed (prep-kernel cost + random 1KiB codes
// reads lose DRAM row locality). Reverted. R3: direct order, 4 samples per wave
// with quarter-wave (16-lane) ownership:
//   - codes reads stay dense/sequential (each load instr covers 4x256B of a
//     contiguous 4KiB window)
//   - butterfly reduction: 4 stages over 16 lanes, shared by 4 samples
//     -> 4 cross-lane ops/sample instead of 24
//   - nontemporal codes loads keep the 3.9 MiB centroid table resident in L2
// HBM floor: 256MiB codes + ~4MB centroids + 1MB out ~= 43 us.

#define B_TOTAL     262144
#define NUM_CLASSES 1000
#define KC          4
#define DIM         256

typedef float vf4 __attribute__((ext_vector_type(4)));

__global__ __launch_bounds__(256) void sparse_codebook_q4(
    const float* __restrict__ codes,
    const int*   __restrict__ pred_class,
    const float* __restrict__ centroids,
    float*       __restrict__ out)
{
    const int wave = (blockIdx.x * 256 + threadIdx.x) >> 6;
    const int lane = threadIdx.x & 63;
    const int q    = lane >> 4;      // quarter 0..3 -> which of the 4 samples
    const int l    = lane & 15;      // lane within quarter
    const int s0   = wave * 4;       // first sample of this wave (B % 4 == 0)
    if (s0 >= B_TOTAL) return;

    const int my_sample = s0 + q;
    const int cls = pred_class[my_sample];   // 4 distinct addrs per wave (1 line)

    // codes row = 256 floats = 64 vf4 chunks; this lane covers chunks j*16+l.
    const vf4* crow = (const vf4*)codes + (size_t)my_sample * 64;
    vf4 c[4];
#pragma unroll
    for (int j = 0; j < 4; ++j)
        c[j] = __builtin_nontemporal_load(&crow[j * 16 + l]);

    // class block: KC*DIM floats = 256 vf4 chunks; row k chunk j*16+l.
    const vf4* cbase = (const vf4*)centroids + (size_t)cls * (KC * DIM / 4);

    float s[KC];
#pragma unroll
    for (int k = 0; k < KC; ++k) {
        float acc = 0.0f;
#pragma unroll
        for (int j = 0; j < 4; ++j) {
            const vf4 g = cbase[k * 16 * 4 + j * 16 + l];
            acc += fabsf(c[j].x - g.x) + fabsf(c[j].y - g.y)
                 + fabsf(c[j].z - g.z) + fabsf(c[j].w - g.w);
        }
        s[k] = acc;
    }

    // reduce each s[k] across the 16 lanes of this quarter (masks 8,4,2,1 stay
    // inside the quarter); serves all 4 samples simultaneously.
#pragma unroll
    for (int off = 8; off >= 1; off >>= 1) {
#pragma unroll
        for (int k = 0; k < KC; ++k)
            s[k] += __shfl_xor(s[k], off, 64);
    }

    if (l == 0) {
        const float m = fminf(fminf(s[0], s[1]), fminf(s[2], s[3]));
        out[my_sample] = m * (1.0f / (float)DIM);   // 4 contiguous floats/wave
    }
}

extern "C" void kernel_launch(void* const* d_in, const int* in_sizes, int n_in,
                              void* d_out, int out_size, void* d_ws, size_t ws_size,
                              hipStream_t stream) {
    const float* codes = (const float*)d_in[0];
    const int*   pred  = (const int*)d_in[1];
    const float* cents = (const float*)d_in[2];
    float*       out   = (float*)d_out;

    // 4 samples per wave -> B/4 waves -> B*16 threads
    const int total_threads = B_TOTAL * 16;
    const int block = 256;
    const int grid  = total_threads / block;  // 16384
    sparse_codebook_q4<<<grid, block, 0, stream>>>(codes, pred, cents, out);
}

// Round 4
// 362.033 us; speedup vs baseline: 1.3799x; 1.0402x over previous
//
#include <hip/hip_runtime.h>

// SparseCodebook: out[b] = min_k mean_d |codes[b,d] - centroids[cls[b],k,d]|
// B=262144, NUM_CLASSES=1000, K=4, D=256.
//
// R3 post-mortem: instruction restructuring is neutral -> BW-bound. Kernel
// moves 256 MiB codes (compulsory HBM) + 1 GiB fp32 centroid gathers; the
// 3.9 MiB fp32 table thrashes the 4 MiB/XCD L2 under stream pressure, so
// gathers fall to L3 (~10 TB/s) -> ~130 us kernel.
// R4: centroids fp32->fp16 into d_ws (2 MB table, L2-resident even under
// streaming; gather bytes halve to 512 MB). Accuracy: fp16 rounding adds
// <=2.4e-4 to each mean (threshold 7.27e-3, current absmax 1.95e-3).

#define B_TOTAL     262144
#define NUM_CLASSES 1000
#define KC          4
#define DIM         256

typedef float    vf4 __attribute__((ext_vector_type(4)));
typedef _Float16 vh4 __attribute__((ext_vector_type(4)));

// centroids fp32 -> fp16 into ws. 1000*4*256 = 1,024,000 elems = 256,000 vf4.
__global__ __launch_bounds__(256) void convert_kernel(
    const float* __restrict__ cent_f32, _Float16* __restrict__ cent_f16)
{
    const int i = blockIdx.x * 256 + threadIdx.x;           // vf4 index
    const int n = NUM_CLASSES * KC * DIM / 4;               // 256,000
    if (i < n) {
        const vf4 v = ((const vf4*)cent_f32)[i];
        vh4 h;
        h.x = (_Float16)v.x; h.y = (_Float16)v.y;
        h.z = (_Float16)v.z; h.w = (_Float16)v.w;
        ((vh4*)cent_f16)[i] = h;
    }
}

// 4 samples per wave; each 16-lane quarter owns one sample.
// Lane covers dims [4*(j*16+l), +4) for j=0..3.
__global__ __launch_bounds__(256) void sparse_codebook_h(
    const float*    __restrict__ codes,
    const int*      __restrict__ pred_class,
    const _Float16* __restrict__ cent_f16,
    float*          __restrict__ out)
{
    const int wave = (blockIdx.x * 256 + threadIdx.x) >> 6;
    const int lane = threadIdx.x & 63;
    const int q    = lane >> 4;
    const int l    = lane & 15;
    const int s0   = wave * 4;
    if (s0 >= B_TOTAL) return;

    const int my_sample = s0 + q;
    const int cls = pred_class[my_sample];

    // codes row: 64 vf4 chunks; nontemporal (one-pass stream, keep L2 for table)
    const vf4* crow = (const vf4*)codes + (size_t)my_sample * 64;
    vf4 c[4];
#pragma unroll
    for (int j = 0; j < 4; ++j)
        c[j] = __builtin_nontemporal_load(&crow[j * 16 + l]);

    // fp16 class block: KC rows x 64 vh4 chunks (8 B/lane gathers, L2-resident)
    const vh4* cbase = (const vh4*)cent_f16 + (size_t)cls * (KC * DIM / 4);

    float s[KC];
#pragma unroll
    for (int k = 0; k < KC; ++k) {
        float acc = 0.0f;
#pragma unroll
        for (int j = 0; j < 4; ++j) {
            const vh4 g = cbase[k * 64 + j * 16 + l];
            acc += fabsf(c[j].x - (float)g.x) + fabsf(c[j].y - (float)g.y)
                 + fabsf(c[j].z - (float)g.z) + fabsf(c[j].w - (float)g.w);
        }
        s[k] = acc;
    }

    // reduce across the 16 lanes of this quarter (xor masks stay in-quarter)
#pragma unroll
    for (int off = 8; off >= 1; off >>= 1) {
#pragma unroll
        for (int k = 0; k < KC; ++k)
            s[k] += __shfl_xor(s[k], off, 64);
    }

    if (l == 0) {
        const float m = fminf(fminf(s[0], s[1]), fminf(s[2], s[3]));
        __builtin_nontemporal_store(m * (1.0f / (float)DIM), &out[my_sample]);
    }
}

extern "C" void kernel_launch(void* const* d_in, const int* in_sizes, int n_in,
                              void* d_out, int out_size, void* d_ws, size_t ws_size,
                              hipStream_t stream) {
    const float* codes = (const float*)d_in[0];
    const int*   pred  = (const int*)d_in[1];
    const float* cents = (const float*)d_in[2];
    float*       out   = (float*)d_out;
    _Float16*    tab   = (_Float16*)d_ws;   // 2 MB fp16 centroid table

    const int nvec = NUM_CLASSES * KC * DIM / 4;  // 256,000
    convert_kernel<<<(nvec + 255) / 256, 256, 0, stream>>>(cents, tab);

    const int grid = (B_TOTAL * 16) / 256;        // 4 samples/wave -> 16384
    sparse_codebook_h<<<grid, 256, 0, stream>>>(codes, pred, tab, out);
}